// Round 5
// baseline (661.646 us; speedup 1.0000x reference)
//
#include <hip/hip_runtime.h>
#include <hip/hip_bf16.h>

// KNN_itc: out[b][n] = sum over support descriptors m (441) of top-3 (over 441
// query descriptors) cosine similarities, C=640, bf16 MFMA.
//
// R10 (vs R9 FAILED-correctness):
//  - R9's only bug: grid 8*188 undersized; j8/20 must reach 9 -> need 200
//    slots/XCD (10 image-groups x 20 blocks). Images 72..74 were missing 12
//    of 20 tile-blocks -> absmax 144. Fixed: grid = 8*200. No other change.
//  - R9 structure (untested perf): R6's proven 2-barrier slab schedule with
//    output tile widened 448x64 -> 448x112 (NJ=7 col-chunks). Blocks/image
//    35 -> 20; staged traffic 1.68GB -> 1.05GB; per-slab intensity 57 -> 100
//    FLOP/B; MFMA floor (46us) now dominant over L2 (31us) / LDS (35us).
//  - norm/pack unchanged from R6 (bank-conflict-free, fragment-linear chunks).

#define B_IMGS 75
#define N_CLS  5
#define C_DIM  640
#define HW     441
#define HWP    448
#define NKT    20            // 640 / 32 k-chunks
#define NRB    28            // 448 / 16 row-blocks per image
#define CHUNK  512           // 16 rows x 32 k elems = 1 KiB
#define TPAD   66            // pack tile pad
#define NJ     7             // col-chunks (16 cols) per gemm block = 112 cols
#define NCHK   (56 + 2 * NJ) // chunks per slab = 70

typedef __attribute__((ext_vector_type(8))) short  short8;   // 8 x bf16
typedef __attribute__((ext_vector_type(4))) float  float4v;  // MFMA acc

__device__ __forceinline__ void ins3(float& t0, float& t1, float& t2, float v) {
    float m  = fminf(t0, v);
    t0 = fmaxf(t0, v);
    float m2 = fminf(t1, m);
    t1 = fmaxf(t1, m);
    t2 = fmaxf(t2, m2);
}

__device__ __forceinline__ void glds16(const __hip_bfloat16* g, __hip_bfloat16* l) {
    __builtin_amdgcn_global_load_lds(
        (const __attribute__((address_space(1))) unsigned int*)g,
        (__attribute__((address_space(3))) unsigned int*)l, 16, 0, 0);
}

// ---- P1: L2 norms. block=(img, 64-hw tile); 560 blocks x 256 thr ----
__global__ __launch_bounds__(256)
void norm_kernel(const float* __restrict__ q, const float* __restrict__ S,
                 float* __restrict__ invn) {
    __shared__ float part[4][64];
    int bid = blockIdx.x;
    int img = bid / 7;               // 0..79 (0..74 = q, 75..79 = S)
    int h0  = bid % 7;
    const float* src = (img < B_IMGS)
        ? q + (size_t)img * C_DIM * HW
        : S + (size_t)(img - B_IMGS) * C_DIM * HW;
    int t  = threadIdx.x;
    int hl = t & 63;
    int p  = t >> 6;                 // 160-channel slice
    int hw = h0 * 64 + hl;
    int hwc = (hw < HW) ? hw : (HW - 1);

    float ss = 0.f;
    // manual 16-deep batches: 16 loads in flight per wave
    for (int c0 = p * 160; c0 < (p + 1) * 160; c0 += 16) {
        float v[16];
#pragma unroll
        for (int j = 0; j < 16; ++j) v[j] = src[(size_t)(c0 + j) * HW + hwc];
#pragma unroll
        for (int j = 0; j < 16; ++j) ss += v[j] * v[j];
    }
    part[p][hl] = ss;
    __syncthreads();
    if (t < 64) {
        float tot = part[0][t] + part[1][t] + part[2][t] + part[3][t];
        // pad rows (hw>=441) -> 0 so packed pad descriptors are zeros
        invn[img * HWP + h0 * 64 + t] = (h0 * 64 + t < HW) ? rsqrtf(tot) : 0.f;
    }
}

// ---- P2: normalize + bf16 + fragment-linear chunk writes ----
// block=(img, h0, ktg): 80*7*5 = 2800 blocks x 256 thr; 16.9KB LDS
// chunk layout: elem(row=r16, k32) at oct*128 + r16*8 + (k32&7), oct=k32>>3
//   -> gemm lane l reads elems [l*8, l*8+8): row=l&15, k32=(l>>4)*8+j  (MFMA frag)
__global__ __launch_bounds__(256)
void pack_kernel(const float* __restrict__ q, const float* __restrict__ S,
                 const float* __restrict__ invn,
                 __hip_bfloat16* __restrict__ qn2, __hip_bfloat16* __restrict__ sn2) {
    __shared__ __hip_bfloat16 tile[128][TPAD];   // [c_local][hw_local]
    int bid = blockIdx.x;
    int img = bid / 35;              // 0..79
    int rem = bid % 35;
    int h0  = rem / 5;               // 0..6
    int ktg = rem % 5;               // 0..4 -> channels ktg*128..+127
    const float* src; __hip_bfloat16* dst;
    if (img < B_IMGS) {
        src = q + (size_t)img * C_DIM * HW;
        dst = qn2 + (size_t)img * NRB * NKT * CHUNK;
    } else {
        src = S + (size_t)(img - B_IMGS) * C_DIM * HW;
        dst = sn2 + (size_t)(img - B_IMGS) * NRB * NKT * CHUNK;
    }
    int t  = threadIdx.x;
    int hl = t & 63;
    int p  = t >> 6;                 // 32-channel slice / wave id
    int hw = h0 * 64 + hl;
    int hwc = (hw < HW) ? hw : (HW - 1);
    float iv = invn[img * HWP + h0 * 64 + hl];   // pad rows -> 0

    // stage: 128 c x 64 hw, scaled, single-rounded bf16, [c][hw]
    for (int c0 = p * 32; c0 < p * 32 + 32; c0 += 8) {
        float v[8];
#pragma unroll
        for (int j = 0; j < 8; ++j)
            v[j] = src[(size_t)(ktg * 128 + c0 + j) * HW + hwc];
#pragma unroll
        for (int j = 0; j < 8; ++j)
            tile[c0 + j][hl] = __float2bfloat16(v[j] * iv);
    }
    __syncthreads();

    // pack: wave p owns chunk rb=h0*4+p; lane tl writes bytes [tl*16, tl*16+16)
    int tl  = t & 63;
    int row = tl & 15;
    int oct = tl >> 4;
    int rb  = h0 * 4 + p;
    for (int ktl = 0; ktl < 4; ++ktl) {
        int kt = ktg * 4 + ktl;
        short8 v;
#pragma unroll
        for (int j = 0; j < 8; ++j) {
            // banks: oct -> +8, row pairs share a dword (broadcast): conflict-free
            __hip_bfloat16 hv = tile[ktl * 32 + oct * 8 + j][p * 16 + row];
            v[j] = *(short*)&hv;
        }
        *(short8*)(dst + ((size_t)rb * NKT + kt) * CHUNK + tl * 8) = v;
    }
}

// ------- gemm + fused top-3: R6 schedule, 448x112 tile -------
__global__ __launch_bounds__(256, 2)
void gemm_top3_kernel(const __hip_bfloat16* __restrict__ qn2,
                      const __hip_bfloat16* __restrict__ sn2,
                      float* __restrict__ out) {
    __shared__ __hip_bfloat16 sbuf[NCHK * CHUNK];   // 70 KiB: 56 A + 14 B chunks
    __shared__ float mrg[4][NJ * 16][3];            // 5.25 KiB

    // XCD-grouping swizzle: all 20 (n,ct) blocks of image b on one XCD
    int id  = blockIdx.x;
    int xcd = id & 7;
    int j8  = id >> 3;               // 0..199
    int b   = (j8 / 20) * 8 + xcd;   // image groups 0..9 -> b 0..79
    if (b >= B_IMGS) return;
    int inner = j8 % 20;
    int n  = inner / 4;              // class 0..4
    int ct = inner % 4;              // col tile 0..3 (112 cols each)

    int tid  = threadIdx.x;
    int w    = tid >> 6;
    int lane = tid & 63;
    int c16  = lane & 15;
    int quad = lane >> 4;
    int frag = lane * 8;   // lane-linear fragment read: conflict-free b128

    const __hip_bfloat16* qA = qn2 + (size_t)b * NRB * NKT * CHUNK;
    const __hip_bfloat16* qB = sn2 + ((size_t)n * NRB + ct * NJ) * NKT * CHUNK;

    float4v acc[7][NJ];
#pragma unroll
    for (int r = 0; r < 7; ++r)
#pragma unroll
        for (int j = 0; j < NJ; ++j)
            acc[r][j] = (float4v){0.f, 0.f, 0.f, 0.f};

    for (int s = 0; s < 10; ++s) {
        __syncthreads();                 // prior slab's ds_reads complete
        // stage 70 chunks; wave w moves chunks [w*18, min(w*18+18, 70))
#pragma unroll
        for (int i = 0; i < 18; ++i) {
            int cid = w * 18 + i;
            if (cid < NCHK) {
                const __hip_bfloat16* g;
                if (cid < 56) {
                    int rb = cid >> 1;
                    g = qA + ((size_t)rb * NKT + 2 * s + (cid & 1)) * CHUNK;
                } else {
                    int local = cid - 56;
                    int jb = local >> 1;
                    g = qB + ((size_t)jb * NKT + 2 * s + (local & 1)) * CHUNK;
                }
                glds16(g + lane * 8, sbuf + cid * CHUNK + lane * 8);
            }
        }
        __syncthreads();                 // vmcnt(0)+barrier: staging visible

#pragma unroll
        for (int kk = 0; kk < 2; ++kk) {
            short8 a[7];
#pragma unroll
            for (int r = 0; r < 7; ++r)
                a[r] = *(const short8*)(sbuf + ((r * 4 + w) * 2 + kk) * CHUNK + frag);
#pragma unroll
            for (int j = 0; j < NJ; ++j) {
                short8 bb = *(const short8*)(sbuf + (56 + j * 2 + kk) * CHUNK + frag);
#pragma unroll
                for (int r = 0; r < 7; ++r)
                    acc[r][j] = __builtin_amdgcn_mfma_f32_16x16x32_bf16(
                        a[r], bb, acc[r][j], 0, 0, 0);
            }
        }
    }

    // ---- in-register top-3 over this wave's 112 rows, per owned column ----
    float T0[NJ], T1[NJ], T2[NJ];
#pragma unroll
    for (int j = 0; j < NJ; ++j) { T0[j] = -1e30f; T1[j] = -1e30f; T2[j] = -1e30f; }
#pragma unroll
    for (int r = 0; r < 7; ++r)
#pragma unroll
        for (int j = 0; j < NJ; ++j)
#pragma unroll
            for (int g = 0; g < 4; ++g) {
                int row = r * 64 + w * 16 + quad * 4 + g;   // C layout: row=quad*4+reg
                float v = (row < HW) ? acc[r][j][g] : -1e30f;
                ins3(T0[j], T1[j], T2[j], v);
            }

    // quad-butterfly merge (rows spread over lane bits 4,5)
#pragma unroll
    for (int j = 0; j < NJ; ++j) {
#pragma unroll
        for (int d = 16; d <= 32; d <<= 1) {
            float o0 = __shfl_xor(T0[j], d, 64);
            float o1 = __shfl_xor(T1[j], d, 64);
            float o2 = __shfl_xor(T2[j], d, 64);
            ins3(T0[j], T1[j], T2[j], o0);
            ins3(T0[j], T1[j], T2[j], o1);
            ins3(T0[j], T1[j], T2[j], o2);
        }
    }

    // cross-wave merge via LDS
    if (quad == 0) {
#pragma unroll
        for (int j = 0; j < NJ; ++j) {
            mrg[w][j * 16 + c16][0] = T0[j];
            mrg[w][j * 16 + c16][1] = T1[j];
            mrg[w][j * 16 + c16][2] = T2[j];
        }
    }
    __syncthreads();
    if (tid < 64) {
        float s = 0.f;
#pragma unroll
        for (int half = 0; half < 2; ++half) {
            int col = tid + half * 64;
            if (col < NJ * 16) {
                float t0 = mrg[0][col][0], t1 = mrg[0][col][1], t2 = mrg[0][col][2];
#pragma unroll
                for (int ww = 1; ww < 4; ++ww) {
                    ins3(t0, t1, t2, mrg[ww][col][0]);
                    ins3(t0, t1, t2, mrg[ww][col][1]);
                    ins3(t0, t1, t2, mrg[ww][col][2]);
                }
                if (ct * (NJ * 16) + col < HW) s += t0 + t1 + t2;
            }
        }
#pragma unroll
        for (int d = 32; d >= 1; d >>= 1) s += __shfl_xor(s, d, 64);
        if (tid == 0) atomicAdd(&out[b * N_CLS + n], s);
    }
}

extern "C" void kernel_launch(void* const* d_in, const int* in_sizes, int n_in,
                              void* d_out, int out_size, void* d_ws, size_t ws_size,
                              hipStream_t stream) {
    const float* q = (const float*)d_in[0];
    const float* S = (const float*)d_in[1];
    float* out = (float*)d_out;

    char* ws = (char*)d_ws;
    size_t off = 0;
    __hip_bfloat16* qn2 = (__hip_bfloat16*)(ws + off);
    off += (size_t)B_IMGS * NRB * NKT * CHUNK * 2;  off = (off + 255) & ~(size_t)255;
    __hip_bfloat16* sn2 = (__hip_bfloat16*)(ws + off);
    off += (size_t)N_CLS * NRB * NKT * CHUNK * 2;   off = (off + 255) & ~(size_t)255;
    float* invn = (float*)(ws + off);

    hipMemsetAsync(d_out, 0, (size_t)out_size * sizeof(float), stream);

    norm_kernel<<<dim3(80 * 7), dim3(256), 0, stream>>>(q, S, invn);
    pack_kernel<<<dim3(80 * 7 * 5), dim3(256), 0, stream>>>(q, S, invn, qn2, sn2);
    // 8 XCDs x 200 slots (10 image-groups x 20 blocks); b>=75 slots exit
    gemm_top3_kernel<<<dim3(8 * 200), dim3(256), 0, stream>>>(qn2, sn2, out);
}

// Round 6
// 486.480 us; speedup vs baseline: 1.3601x; 1.3601x over previous
//
#include <hip/hip_runtime.h>
#include <hip/hip_bf16.h>

// KNN_itc: out[b][n] = sum over support descriptors m (441) of top-3 (over 441
// query descriptors) cosine similarities, C=640, bf16 MFMA.
//
// R11 (vs R10 FAILED-spill, vs R6 best=135us gemm / 284us total):
//  - R10 post-mortem: 448x112 tile -> acc[7][7]=196 f32/thread > register
//    budget -> scratch spill (WRITE_SIZE 82KB->251MB, MfmaUtil 7.5%). No
//    register-feasible wider-BN tile exists (448 chunk divisors force BN
//    64/112/224; 112+ overflows acc at any integer wave split). Abandoned.
//  - R11: back to R6's exact 448x64 tile + 2-barrier slab schedule, but
//    BK 64 -> 32: slab = 32 chunks (28 A + 4 B) = 32KB, LDS ~35KB ->
//    4 independent blocks/CU (was 2). Same total glds/ds_read/MFMA; the
//    vmcnt(0) drain at each barrier is now hidden by 3 other phase-staggered
//    blocks per CU. __launch_bounds__(256,4) (VGPR cap 128; R6 used 124).
//  - norm/pack unchanged from R6 (bank-conflict-free, fragment-linear chunks).

#define B_IMGS 75
#define N_CLS  5
#define C_DIM  640
#define HW     441
#define HWP    448
#define NKT    20            // 640 / 32 k-chunks
#define NRB    28            // 448 / 16 row-blocks per image
#define CHUNK  512           // 16 rows x 32 k elems = 1 KiB
#define TPAD   66            // pack tile pad

typedef __attribute__((ext_vector_type(8))) short  short8;   // 8 x bf16
typedef __attribute__((ext_vector_type(4))) float  float4v;  // MFMA acc

__device__ __forceinline__ void ins3(float& t0, float& t1, float& t2, float v) {
    float m  = fminf(t0, v);
    t0 = fmaxf(t0, v);
    float m2 = fminf(t1, m);
    t1 = fmaxf(t1, m);
    t2 = fmaxf(t2, m2);
}

__device__ __forceinline__ void glds16(const __hip_bfloat16* g, __hip_bfloat16* l) {
    __builtin_amdgcn_global_load_lds(
        (const __attribute__((address_space(1))) unsigned int*)g,
        (__attribute__((address_space(3))) unsigned int*)l, 16, 0, 0);
}

// ---- P1: L2 norms. block=(img, 64-hw tile); 560 blocks x 256 thr ----
__global__ __launch_bounds__(256)
void norm_kernel(const float* __restrict__ q, const float* __restrict__ S,
                 float* __restrict__ invn) {
    __shared__ float part[4][64];
    int bid = blockIdx.x;
    int img = bid / 7;               // 0..79 (0..74 = q, 75..79 = S)
    int h0  = bid % 7;
    const float* src = (img < B_IMGS)
        ? q + (size_t)img * C_DIM * HW
        : S + (size_t)(img - B_IMGS) * C_DIM * HW;
    int t  = threadIdx.x;
    int hl = t & 63;
    int p  = t >> 6;                 // 160-channel slice
    int hw = h0 * 64 + hl;
    int hwc = (hw < HW) ? hw : (HW - 1);

    float ss = 0.f;
    // manual 16-deep batches: 16 loads in flight per wave
    for (int c0 = p * 160; c0 < (p + 1) * 160; c0 += 16) {
        float v[16];
#pragma unroll
        for (int j = 0; j < 16; ++j) v[j] = src[(size_t)(c0 + j) * HW + hwc];
#pragma unroll
        for (int j = 0; j < 16; ++j) ss += v[j] * v[j];
    }
    part[p][hl] = ss;
    __syncthreads();
    if (t < 64) {
        float tot = part[0][t] + part[1][t] + part[2][t] + part[3][t];
        // pad rows (hw>=441) -> 0 so packed pad descriptors are zeros
        invn[img * HWP + h0 * 64 + t] = (h0 * 64 + t < HW) ? rsqrtf(tot) : 0.f;
    }
}

// ---- P2: normalize + bf16 + fragment-linear chunk writes ----
// block=(img, h0, ktg): 80*7*5 = 2800 blocks x 256 thr; 16.9KB LDS
// chunk layout: elem(row=r16, k32) at oct*128 + r16*8 + (k32&7), oct=k32>>3
//   -> gemm lane l reads elems [l*8, l*8+8): row=l&15, k32=(l>>4)*8+j  (MFMA frag)
__global__ __launch_bounds__(256)
void pack_kernel(const float* __restrict__ q, const float* __restrict__ S,
                 const float* __restrict__ invn,
                 __hip_bfloat16* __restrict__ qn2, __hip_bfloat16* __restrict__ sn2) {
    __shared__ __hip_bfloat16 tile[128][TPAD];   // [c_local][hw_local]
    int bid = blockIdx.x;
    int img = bid / 35;              // 0..79
    int rem = bid % 35;
    int h0  = rem / 5;               // 0..6
    int ktg = rem % 5;               // 0..4 -> channels ktg*128..+127
    const float* src; __hip_bfloat16* dst;
    if (img < B_IMGS) {
        src = q + (size_t)img * C_DIM * HW;
        dst = qn2 + (size_t)img * NRB * NKT * CHUNK;
    } else {
        src = S + (size_t)(img - B_IMGS) * C_DIM * HW;
        dst = sn2 + (size_t)(img - B_IMGS) * NRB * NKT * CHUNK;
    }
    int t  = threadIdx.x;
    int hl = t & 63;
    int p  = t >> 6;                 // 32-channel slice / wave id
    int hw = h0 * 64 + hl;
    int hwc = (hw < HW) ? hw : (HW - 1);
    float iv = invn[img * HWP + h0 * 64 + hl];   // pad rows -> 0

    // stage: 128 c x 64 hw, scaled, single-rounded bf16, [c][hw]
    for (int c0 = p * 32; c0 < p * 32 + 32; c0 += 8) {
        float v[8];
#pragma unroll
        for (int j = 0; j < 8; ++j)
            v[j] = src[(size_t)(ktg * 128 + c0 + j) * HW + hwc];
#pragma unroll
        for (int j = 0; j < 8; ++j)
            tile[c0 + j][hl] = __float2bfloat16(v[j] * iv);
    }
    __syncthreads();

    // pack: wave p owns chunk rb=h0*4+p; lane tl writes bytes [tl*16, tl*16+16)
    int tl  = t & 63;
    int row = tl & 15;
    int oct = tl >> 4;
    int rb  = h0 * 4 + p;
    for (int ktl = 0; ktl < 4; ++ktl) {
        int kt = ktg * 4 + ktl;
        short8 v;
#pragma unroll
        for (int j = 0; j < 8; ++j) {
            // banks: oct -> +8, row pairs share a dword (broadcast): conflict-free
            __hip_bfloat16 hv = tile[ktl * 32 + oct * 8 + j][p * 16 + row];
            v[j] = *(short*)&hv;
        }
        *(short8*)(dst + ((size_t)rb * NKT + kt) * CHUNK + tl * 8) = v;
    }
}

// ---- gemm + fused top-3: R6 schedule, BK=32 -> 4 blocks/CU ----
__global__ __launch_bounds__(256, 4)
void gemm_top3_kernel(const __hip_bfloat16* __restrict__ qn2,
                      const __hip_bfloat16* __restrict__ sn2,
                      float* __restrict__ out) {
    __shared__ __hip_bfloat16 sbuf[32 * CHUNK];   // 32 KiB: 28 A + 4 B chunks
    __shared__ float mrg[4][64][3];

    // XCD-grouping swizzle: all 35 (n,mt) blocks of image b on one XCD
    int id  = blockIdx.x;
    int xcd = id & 7;
    int j8  = id >> 3;
    int b   = (j8 / 35) * 8 + xcd;
    if (b >= B_IMGS) return;
    int inner = j8 % 35;
    int n  = inner / 7;
    int mt = inner % 7;

    int tid  = threadIdx.x;
    int w    = tid >> 6;
    int lane = tid & 63;
    int c16  = lane & 15;
    int quad = lane >> 4;
    int frag = lane * 8;   // lane-linear fragment read: conflict-free b128

    const __hip_bfloat16* qA = qn2 + (size_t)b * NRB * NKT * CHUNK;
    const __hip_bfloat16* qB = sn2 + ((size_t)n * NRB + mt * 4) * NKT * CHUNK;

    float4v acc[7][4];
#pragma unroll
    for (int r = 0; r < 7; ++r)
#pragma unroll
        for (int j = 0; j < 4; ++j)
            acc[r][j] = (float4v){0.f, 0.f, 0.f, 0.f};

    for (int s = 0; s < NKT; ++s) {
        __syncthreads();                 // prior slab's ds_reads complete
        // stage 32 chunks (28 A + 4 B); wave w moves chunks [w*8, w*8+8)
#pragma unroll
        for (int i = 0; i < 8; ++i) {
            int cid = w * 8 + i;
            const __hip_bfloat16* g = (cid < 28)
                ? qA + ((size_t)cid * NKT + s) * CHUNK
                : qB + ((size_t)(cid - 28) * NKT + s) * CHUNK;
            glds16(g + lane * 8, sbuf + cid * CHUNK + lane * 8);
        }
        __syncthreads();                 // vmcnt(0)+barrier: staging visible

        short8 a[7], bfr[4];
#pragma unroll
        for (int r = 0; r < 7; ++r)
            a[r] = *(const short8*)(sbuf + (r * 4 + w) * CHUNK + frag);
#pragma unroll
        for (int j = 0; j < 4; ++j)
            bfr[j] = *(const short8*)(sbuf + (28 + j) * CHUNK + frag);
#pragma unroll
        for (int r = 0; r < 7; ++r)
#pragma unroll
            for (int j = 0; j < 4; ++j)
                acc[r][j] = __builtin_amdgcn_mfma_f32_16x16x32_bf16(
                    a[r], bfr[j], acc[r][j], 0, 0, 0);
    }

    // ---- in-register top-3 over this wave's 112 rows, per owned column ----
    float T0[4], T1[4], T2[4];
#pragma unroll
    for (int j = 0; j < 4; ++j) { T0[j] = -1e30f; T1[j] = -1e30f; T2[j] = -1e30f; }
#pragma unroll
    for (int r = 0; r < 7; ++r)
#pragma unroll
        for (int j = 0; j < 4; ++j)
#pragma unroll
            for (int g = 0; g < 4; ++g) {
                int row = r * 64 + w * 16 + quad * 4 + g;   // C layout: row=quad*4+reg
                float v = (row < HW) ? acc[r][j][g] : -1e30f;
                ins3(T0[j], T1[j], T2[j], v);
            }

    // quad-butterfly merge (rows spread over lane bits 4,5)
#pragma unroll
    for (int j = 0; j < 4; ++j) {
#pragma unroll
        for (int d = 16; d <= 32; d <<= 1) {
            float o0 = __shfl_xor(T0[j], d, 64);
            float o1 = __shfl_xor(T1[j], d, 64);
            float o2 = __shfl_xor(T2[j], d, 64);
            ins3(T0[j], T1[j], T2[j], o0);
            ins3(T0[j], T1[j], T2[j], o1);
            ins3(T0[j], T1[j], T2[j], o2);
        }
    }

    // cross-wave merge via LDS
    if (quad == 0) {
#pragma unroll
        for (int j = 0; j < 4; ++j) {
            mrg[w][j * 16 + c16][0] = T0[j];
            mrg[w][j * 16 + c16][1] = T1[j];
            mrg[w][j * 16 + c16][2] = T2[j];
        }
    }
    __syncthreads();
    if (tid < 64) {
        int col = tid;
        float t0 = mrg[0][col][0], t1 = mrg[0][col][1], t2 = mrg[0][col][2];
#pragma unroll
        for (int ww = 1; ww < 4; ++ww) {
            ins3(t0, t1, t2, mrg[ww][col][0]);
            ins3(t0, t1, t2, mrg[ww][col][1]);
            ins3(t0, t1, t2, mrg[ww][col][2]);
        }
        float s = (mt * 64 + col < HW) ? (t0 + t1 + t2) : 0.f;
#pragma unroll
        for (int d = 32; d >= 1; d >>= 1) s += __shfl_xor(s, d, 64);
        if (tid == 0) atomicAdd(&out[b * N_CLS + n], s);
    }
}

extern "C" void kernel_launch(void* const* d_in, const int* in_sizes, int n_in,
                              void* d_out, int out_size, void* d_ws, size_t ws_size,
                              hipStream_t stream) {
    const float* q = (const float*)d_in[0];
    const float* S = (const float*)d_in[1];
    float* out = (float*)d_out;

    char* ws = (char*)d_ws;
    size_t off = 0;
    __hip_bfloat16* qn2 = (__hip_bfloat16*)(ws + off);
    off += (size_t)B_IMGS * NRB * NKT * CHUNK * 2;  off = (off + 255) & ~(size_t)255;
    __hip_bfloat16* sn2 = (__hip_bfloat16*)(ws + off);
    off += (size_t)N_CLS * NRB * NKT * CHUNK * 2;   off = (off + 255) & ~(size_t)255;
    float* invn = (float*)(ws + off);

    hipMemsetAsync(d_out, 0, (size_t)out_size * sizeof(float), stream);

    norm_kernel<<<dim3(80 * 7), dim3(256), 0, stream>>>(q, S, invn);
    pack_kernel<<<dim3(80 * 7 * 5), dim3(256), 0, stream>>>(q, S, invn, qn2, sn2);
    // 8 XCD groups x 350 slots (35 blocks/image); b>=75 slots exit immediately
    gemm_top3_kernel<<<dim3(8 * 350), dim3(256), 0, stream>>>(qn2, sn2, out);
}

// Round 7
// 264.208 us; speedup vs baseline: 2.5043x; 1.8413x over previous
//
#include <hip/hip_runtime.h>
#include <hip/hip_bf16.h>

// KNN_itc: out[b][n] = sum over support descriptors m (441) of top-3 (over 441
// query descriptors) cosine similarities, C=640, bf16 MFMA.
//
// R12 (vs R11/R10 FAILED-spill, vs R6 best=135us gemm / 284us total):
//  - Lesson locked: acc=112 f32/thread => max 2 blocks/CU. Occupancy lever dead.
//  - R12 deletes LDS from the gemm K-loop entirely. Rationale: A chunks have
//    ZERO cross-wave reuse (rb = r*4+w belongs to one wave) and B only 4-way;
//    the packed layout is fragment-linear, so each wave global_load_dwordx4's
//    its A/B fragments straight to VGPRs (chunk + lane*16B, coalesced 1KB/instr,
//    L2/L3-resident). No glds, no LDS traffic (was 1.68GB wr + 2.95GB rd),
//    NO barriers in the K-loop. B redundancy x4 -> L2 ~2.3GB ~ 67us floor vs
//    barrier-serialized 135us. Register double-buffer with named sets s0/s1
//    (static indices), kt+=2 unroll. VGPR ~215 < 256 cap of (256,2).
//  - Epilogue top-3 + tiny mrg LDS (3KB) unchanged.
//  - norm/pack unchanged from R6 (attribution; prep attacked next round once
//    its dispatches surface in top-5 behind a faster gemm).

#define B_IMGS 75
#define N_CLS  5
#define C_DIM  640
#define HW     441
#define HWP    448
#define NKT    20            // 640 / 32 k-chunks
#define NRB    28            // 448 / 16 row-blocks per image
#define CHUNK  512           // 16 rows x 32 k elems = 1 KiB
#define TPAD   66            // pack tile pad

typedef __attribute__((ext_vector_type(8))) short  short8;   // 8 x bf16
typedef __attribute__((ext_vector_type(4))) float  float4v;  // MFMA acc

__device__ __forceinline__ void ins3(float& t0, float& t1, float& t2, float v) {
    float m  = fminf(t0, v);
    t0 = fmaxf(t0, v);
    float m2 = fminf(t1, m);
    t1 = fmaxf(t1, m);
    t2 = fmaxf(t2, m2);
}

__device__ __forceinline__ void glds16(const __hip_bfloat16* g, __hip_bfloat16* l) {
    __builtin_amdgcn_global_load_lds(
        (const __attribute__((address_space(1))) unsigned int*)g,
        (__attribute__((address_space(3))) unsigned int*)l, 16, 0, 0);
}

// ---- P1: L2 norms. block=(img, 64-hw tile); 560 blocks x 256 thr ----
__global__ __launch_bounds__(256)
void norm_kernel(const float* __restrict__ q, const float* __restrict__ S,
                 float* __restrict__ invn) {
    __shared__ float part[4][64];
    int bid = blockIdx.x;
    int img = bid / 7;               // 0..79 (0..74 = q, 75..79 = S)
    int h0  = bid % 7;
    const float* src = (img < B_IMGS)
        ? q + (size_t)img * C_DIM * HW
        : S + (size_t)(img - B_IMGS) * C_DIM * HW;
    int t  = threadIdx.x;
    int hl = t & 63;
    int p  = t >> 6;                 // 160-channel slice
    int hw = h0 * 64 + hl;
    int hwc = (hw < HW) ? hw : (HW - 1);

    float ss = 0.f;
    // manual 16-deep batches: 16 loads in flight per wave
    for (int c0 = p * 160; c0 < (p + 1) * 160; c0 += 16) {
        float v[16];
#pragma unroll
        for (int j = 0; j < 16; ++j) v[j] = src[(size_t)(c0 + j) * HW + hwc];
#pragma unroll
        for (int j = 0; j < 16; ++j) ss += v[j] * v[j];
    }
    part[p][hl] = ss;
    __syncthreads();
    if (t < 64) {
        float tot = part[0][t] + part[1][t] + part[2][t] + part[3][t];
        // pad rows (hw>=441) -> 0 so packed pad descriptors are zeros
        invn[img * HWP + h0 * 64 + t] = (h0 * 64 + t < HW) ? rsqrtf(tot) : 0.f;
    }
}

// ---- P2: normalize + bf16 + fragment-linear chunk writes ----
// block=(img, h0, ktg): 80*7*5 = 2800 blocks x 256 thr; 16.9KB LDS
// chunk layout: elem(row=r16, k32) at oct*128 + r16*8 + (k32&7), oct=k32>>3
//   -> gemm lane l reads elems [l*8, l*8+8): row=l&15, k32=(l>>4)*8+j  (MFMA frag)
__global__ __launch_bounds__(256)
void pack_kernel(const float* __restrict__ q, const float* __restrict__ S,
                 const float* __restrict__ invn,
                 __hip_bfloat16* __restrict__ qn2, __hip_bfloat16* __restrict__ sn2) {
    __shared__ __hip_bfloat16 tile[128][TPAD];   // [c_local][hw_local]
    int bid = blockIdx.x;
    int img = bid / 35;              // 0..79
    int rem = bid % 35;
    int h0  = rem / 5;               // 0..6
    int ktg = rem % 5;               // 0..4 -> channels ktg*128..+127
    const float* src; __hip_bfloat16* dst;
    if (img < B_IMGS) {
        src = q + (size_t)img * C_DIM * HW;
        dst = qn2 + (size_t)img * NRB * NKT * CHUNK;
    } else {
        src = S + (size_t)(img - B_IMGS) * C_DIM * HW;
        dst = sn2 + (size_t)(img - B_IMGS) * NRB * NKT * CHUNK;
    }
    int t  = threadIdx.x;
    int hl = t & 63;
    int p  = t >> 6;                 // 32-channel slice / wave id
    int hw = h0 * 64 + hl;
    int hwc = (hw < HW) ? hw : (HW - 1);
    float iv = invn[img * HWP + h0 * 64 + hl];   // pad rows -> 0

    // stage: 128 c x 64 hw, scaled, single-rounded bf16, [c][hw]
    for (int c0 = p * 32; c0 < p * 32 + 32; c0 += 8) {
        float v[8];
#pragma unroll
        for (int j = 0; j < 8; ++j)
            v[j] = src[(size_t)(ktg * 128 + c0 + j) * HW + hwc];
#pragma unroll
        for (int j = 0; j < 8; ++j)
            tile[c0 + j][hl] = __float2bfloat16(v[j] * iv);
    }
    __syncthreads();

    // pack: wave p owns chunk rb=h0*4+p; lane tl writes bytes [tl*16, tl*16+16)
    int tl  = t & 63;
    int row = tl & 15;
    int oct = tl >> 4;
    int rb  = h0 * 4 + p;
    for (int ktl = 0; ktl < 4; ++ktl) {
        int kt = ktg * 4 + ktl;
        short8 v;
#pragma unroll
        for (int j = 0; j < 8; ++j) {
            // banks: oct -> +8, row pairs share a dword (broadcast): conflict-free
            __hip_bfloat16 hv = tile[ktl * 32 + oct * 8 + j][p * 16 + row];
            v[j] = *(short*)&hv;
        }
        *(short8*)(dst + ((size_t)rb * NKT + kt) * CHUNK + tl * 8) = v;
    }
}

// ---- gemm + fused top-3: barrier-free, all-register, direct global loads ----
#define LOADSET(aS, bS, kt)                                                     \
    {                                                                           \
        _Pragma("unroll")                                                       \
        for (int r = 0; r < 7; ++r)                                             \
            aS[r] = *(const short8*)(pA + ((size_t)(r * 4 + w) * NKT + (kt)) * CHUNK); \
        _Pragma("unroll")                                                       \
        for (int j = 0; j < 4; ++j)                                             \
            bS[j] = *(const short8*)(pB + ((size_t)j * NKT + (kt)) * CHUNK);    \
    }

#define MFMASET(aS, bS)                                                         \
    {                                                                           \
        _Pragma("unroll")                                                       \
        for (int r = 0; r < 7; ++r)                                             \
            _Pragma("unroll")                                                   \
            for (int j = 0; j < 4; ++j)                                         \
                acc[r][j] = __builtin_amdgcn_mfma_f32_16x16x32_bf16(            \
                    aS[r], bS[j], acc[r][j], 0, 0, 0);                          \
    }

__global__ __launch_bounds__(256, 2)
void gemm_top3_kernel(const __hip_bfloat16* __restrict__ qn2,
                      const __hip_bfloat16* __restrict__ sn2,
                      float* __restrict__ out) {
    __shared__ float mrg[4][64][3];

    // XCD-grouping swizzle: all 35 (n,mt) blocks of image b on one XCD
    int id  = blockIdx.x;
    int xcd = id & 7;
    int j8  = id >> 3;
    int b   = (j8 / 35) * 8 + xcd;
    if (b >= B_IMGS) return;
    int inner = j8 % 35;
    int n  = inner / 7;
    int mt = inner % 7;

    int tid  = threadIdx.x;
    int w    = tid >> 6;
    int lane = tid & 63;
    int c16  = lane & 15;
    int quad = lane >> 4;

    // fragment base: lane l owns bytes [l*16, l*16+16) of each 1KiB chunk
    const __hip_bfloat16* pA = qn2 + (size_t)b * NRB * NKT * CHUNK + lane * 8;
    const __hip_bfloat16* pB = sn2 + ((size_t)n * NRB + mt * 4) * NKT * CHUNK + lane * 8;

    float4v acc[7][4];
#pragma unroll
    for (int r = 0; r < 7; ++r)
#pragma unroll
        for (int j = 0; j < 4; ++j)
            acc[r][j] = (float4v){0.f, 0.f, 0.f, 0.f};

    // register double-buffer, named sets (static indexing), kt+=2 unroll
    short8 a0[7], b0[4], a1[7], b1[4];
    LOADSET(a0, b0, 0)
    for (int kt = 0; kt < NKT; kt += 2) {
        LOADSET(a1, b1, kt + 1)
        MFMASET(a0, b0)
        if (kt + 2 < NKT) LOADSET(a0, b0, kt + 2)
        MFMASET(a1, b1)
    }

    // ---- in-register top-3 over this wave's 112 rows, per owned column ----
    float T0[4], T1[4], T2[4];
#pragma unroll
    for (int j = 0; j < 4; ++j) { T0[j] = -1e30f; T1[j] = -1e30f; T2[j] = -1e30f; }
#pragma unroll
    for (int r = 0; r < 7; ++r)
#pragma unroll
        for (int j = 0; j < 4; ++j)
#pragma unroll
            for (int g = 0; g < 4; ++g) {
                int row = r * 64 + w * 16 + quad * 4 + g;   // C layout: row=quad*4+reg
                float v = (row < HW) ? acc[r][j][g] : -1e30f;
                ins3(T0[j], T1[j], T2[j], v);
            }

    // quad-butterfly merge (rows spread over lane bits 4,5)
#pragma unroll
    for (int j = 0; j < 4; ++j) {
#pragma unroll
        for (int d = 16; d <= 32; d <<= 1) {
            float o0 = __shfl_xor(T0[j], d, 64);
            float o1 = __shfl_xor(T1[j], d, 64);
            float o2 = __shfl_xor(T2[j], d, 64);
            ins3(T0[j], T1[j], T2[j], o0);
            ins3(T0[j], T1[j], T2[j], o1);
            ins3(T0[j], T1[j], T2[j], o2);
        }
    }

    // cross-wave merge via LDS
    if (quad == 0) {
#pragma unroll
        for (int j = 0; j < 4; ++j) {
            mrg[w][j * 16 + c16][0] = T0[j];
            mrg[w][j * 16 + c16][1] = T1[j];
            mrg[w][j * 16 + c16][2] = T2[j];
        }
    }
    __syncthreads();
    if (tid < 64) {
        int col = tid;
        float t0 = mrg[0][col][0], t1 = mrg[0][col][1], t2 = mrg[0][col][2];
#pragma unroll
        for (int ww = 1; ww < 4; ++ww) {
            ins3(t0, t1, t2, mrg[ww][col][0]);
            ins3(t0, t1, t2, mrg[ww][col][1]);
            ins3(t0, t1, t2, mrg[ww][col][2]);
        }
        float s = (mt * 64 + col < HW) ? (t0 + t1 + t2) : 0.f;
#pragma unroll
        for (int d = 32; d >= 1; d >>= 1) s += __shfl_xor(s, d, 64);
        if (tid == 0) atomicAdd(&out[b * N_CLS + n], s);
    }
}

extern "C" void kernel_launch(void* const* d_in, const int* in_sizes, int n_in,
                              void* d_out, int out_size, void* d_ws, size_t ws_size,
                              hipStream_t stream) {
    const float* q = (const float*)d_in[0];
    const float* S = (const float*)d_in[1];
    float* out = (float*)d_out;

    char* ws = (char*)d_ws;
    size_t off = 0;
    __hip_bfloat16* qn2 = (__hip_bfloat16*)(ws + off);
    off += (size_t)B_IMGS * NRB * NKT * CHUNK * 2;  off = (off + 255) & ~(size_t)255;
    __hip_bfloat16* sn2 = (__hip_bfloat16*)(ws + off);
    off += (size_t)N_CLS * NRB * NKT * CHUNK * 2;   off = (off + 255) & ~(size_t)255;
    float* invn = (float*)(ws + off);

    hipMemsetAsync(d_out, 0, (size_t)out_size * sizeof(float), stream);

    norm_kernel<<<dim3(80 * 7), dim3(256), 0, stream>>>(q, S, invn);
    pack_kernel<<<dim3(80 * 7 * 5), dim3(256), 0, stream>>>(q, S, invn, qn2, sn2);
    // 8 XCD groups x 350 slots (35 blocks/image); b>=75 slots exit immediately
    gemm_top3_kernel<<<dim3(8 * 350), dim3(256), 0, stream>>>(qn2, sn2, out);
}

// Round 8
// 256.186 us; speedup vs baseline: 2.5827x; 1.0313x over previous
//
#include <hip/hip_runtime.h>
#include <hip/hip_bf16.h>

// KNN_itc: out[b][n] = sum over support descriptors m (441) of top-3 (over 441
// query descriptors) cosine similarities, C=640, bf16 MFMA.
//
// R13 (vs R12 = 113us gemm / 264us total):
//  - gemm UNCHANGED from R12 (barrier-free, all-register, direct global
//    fragment loads; 113us, MfmaUtil 37%, no spill).
//  - prep: norm+pack fused into ONE kernel, and the hipMemsetAsync launch is
//    deleted (block 0 zeroes out[375] before gemm runs; stream-ordered).
//    Rationale: the non-gemm 151us has been CONSTANT (135-151) across six
//    rounds of radical prep restructuring -> dominated by fixed per-dispatch
//    overhead (4 dependent dispatches), not prep compute (BW floors ~35us).
//    Dispatches per iteration: 4 -> 2.
//  - fused prep, block=(img,h0), 560 blocks x 256 thr, tiny LDS (1.3KB):
//    pass1: 4-wave c-split sumsq (coalesced 256B/instr, 16-deep ILP),
//           LDS-reduce -> inv[64] (pad rows -> 0).
//    pass2: re-read from global (L2/L3-hot block-local 160KB), scale,
//           single-rounded bf16, pack short8 in REGISTERS, store
//           fragment-linear chunks (1KB contiguous per wave) -- no big LDS,
//           no bf16 LDS round-trip, no invn global round-trip.

#define B_IMGS 75
#define N_CLS  5
#define C_DIM  640
#define HW     441
#define HWP    448
#define NKT    20            // 640 / 32 k-chunks
#define NRB    28            // 448 / 16 row-blocks per image
#define CHUNK  512           // 16 rows x 32 k elems = 1 KiB

typedef __attribute__((ext_vector_type(8))) short  short8;   // 8 x bf16
typedef __attribute__((ext_vector_type(4))) float  float4v;  // MFMA acc

__device__ __forceinline__ void ins3(float& t0, float& t1, float& t2, float v) {
    float m  = fminf(t0, v);
    t0 = fmaxf(t0, v);
    float m2 = fminf(t1, m);
    t1 = fmaxf(t1, m);
    t2 = fmaxf(t2, m2);
}

// ---- fused prep: sumsq + normalize + bf16 + fragment-linear pack ----
// block=(img 0..79, h0 0..6); 560 blocks x 256 thr
// chunk layout: elem(row=r16, k32) at oct*128 + r16*8 + (k32&7), oct=k32>>3
//   -> gemm lane l reads elems [l*8, l*8+8): row=l&15, k32=(l>>4)*8+j (MFMA frag)
__global__ __launch_bounds__(256)
void prep_kernel(const float* __restrict__ q, const float* __restrict__ S,
                 __hip_bfloat16* __restrict__ qn2, __hip_bfloat16* __restrict__ sn2,
                 float* __restrict__ out) {
    __shared__ float part[4][64];
    __shared__ float inv[64];

    int bid = blockIdx.x;
    // zero the output accumulator (replaces the hipMemsetAsync dispatch);
    // gemm is a later dispatch on the same stream -> ordering is safe.
    if (bid == 0) {
        for (int i = threadIdx.x; i < B_IMGS * N_CLS; i += 256) out[i] = 0.f;
    }

    int img = bid / 7;               // 0..79 (0..74 = q, 75..79 = S)
    int h0  = bid % 7;
    const float* src; __hip_bfloat16* dst;
    if (img < B_IMGS) {
        src = q + (size_t)img * C_DIM * HW;
        dst = qn2 + (size_t)img * NRB * NKT * CHUNK;
    } else {
        src = S + (size_t)(img - B_IMGS) * C_DIM * HW;
        dst = sn2 + (size_t)(img - B_IMGS) * NRB * NKT * CHUNK;
    }
    int t  = threadIdx.x;
    int hl = t & 63;
    int p  = t >> 6;                 // wave id / 160-channel slice
    int hw = h0 * 64 + hl;
    int hwc = (hw < HW) ? hw : (HW - 1);

    // ---- pass 1: sum of squares over C (coalesced, 16-deep batches) ----
    float ss = 0.f;
    for (int c0 = p * 160; c0 < (p + 1) * 160; c0 += 16) {
        float v[16];
#pragma unroll
        for (int j = 0; j < 16; ++j) v[j] = src[(size_t)(c0 + j) * HW + hwc];
#pragma unroll
        for (int j = 0; j < 16; ++j) ss += v[j] * v[j];
    }
    part[p][hl] = ss;
    __syncthreads();
    if (t < 64) {
        float tot = part[0][t] + part[1][t] + part[2][t] + part[3][t];
        // pad rows (hw>=441) -> 0 so packed pad descriptors are zeros
        inv[t] = (h0 * 64 + t < HW) ? rsqrtf(tot) : 0.f;
    }
    __syncthreads();

    // ---- pass 2: L2/L3-hot re-read, scale, pack in registers, store ----
    // wave p owns chunk rb = h0*4+p; lane tl writes bytes [tl*16, tl*16+16)
    int tl  = hl;
    int row = tl & 15;
    int oct = tl >> 4;
    int rb  = h0 * 4 + p;
    int hw2 = h0 * 64 + p * 16 + row;
    int hw2c = (hw2 < HW) ? hw2 : (HW - 1);
    float iv = inv[p * 16 + row];    // 0 for pad rows
    const float* s2 = src + hw2c;
#pragma unroll 2
    for (int kt = 0; kt < NKT; ++kt) {
        float v[8];
#pragma unroll
        for (int j = 0; j < 8; ++j)
            v[j] = s2[(size_t)(kt * 32 + oct * 8 + j) * HW];
        short8 o;
#pragma unroll
        for (int j = 0; j < 8; ++j) {
            __hip_bfloat16 h = __float2bfloat16(v[j] * iv);
            o[j] = *(short*)&h;
        }
        *(short8*)(dst + ((size_t)rb * NKT + kt) * CHUNK + tl * 8) = o;
    }
}

// ---- gemm + fused top-3: barrier-free, all-register, direct global loads ----
#define LOADSET(aS, bS, kt)                                                     \
    {                                                                           \
        _Pragma("unroll")                                                       \
        for (int r = 0; r < 7; ++r)                                             \
            aS[r] = *(const short8*)(pA + ((size_t)(r * 4 + w) * NKT + (kt)) * CHUNK); \
        _Pragma("unroll")                                                       \
        for (int j = 0; j < 4; ++j)                                             \
            bS[j] = *(const short8*)(pB + ((size_t)j * NKT + (kt)) * CHUNK);    \
    }

#define MFMASET(aS, bS)                                                         \
    {                                                                           \
        _Pragma("unroll")                                                       \
        for (int r = 0; r < 7; ++r)                                             \
            _Pragma("unroll")                                                   \
            for (int j = 0; j < 4; ++j)                                         \
                acc[r][j] = __builtin_amdgcn_mfma_f32_16x16x32_bf16(            \
                    aS[r], bS[j], acc[r][j], 0, 0, 0);                          \
    }

__global__ __launch_bounds__(256, 2)
void gemm_top3_kernel(const __hip_bfloat16* __restrict__ qn2,
                      const __hip_bfloat16* __restrict__ sn2,
                      float* __restrict__ out) {
    __shared__ float mrg[4][64][3];

    // XCD-grouping swizzle: all 35 (n,mt) blocks of image b on one XCD
    int id  = blockIdx.x;
    int xcd = id & 7;
    int j8  = id >> 3;
    int b   = (j8 / 35) * 8 + xcd;
    if (b >= B_IMGS) return;
    int inner = j8 % 35;
    int n  = inner / 7;
    int mt = inner % 7;

    int tid  = threadIdx.x;
    int w    = tid >> 6;
    int lane = tid & 63;
    int c16  = lane & 15;
    int quad = lane >> 4;

    // fragment base: lane l owns bytes [l*16, l*16+16) of each 1KiB chunk
    const __hip_bfloat16* pA = qn2 + (size_t)b * NRB * NKT * CHUNK + lane * 8;
    const __hip_bfloat16* pB = sn2 + ((size_t)n * NRB + mt * 4) * NKT * CHUNK + lane * 8;

    float4v acc[7][4];
#pragma unroll
    for (int r = 0; r < 7; ++r)
#pragma unroll
        for (int j = 0; j < 4; ++j)
            acc[r][j] = (float4v){0.f, 0.f, 0.f, 0.f};

    // register double-buffer, named sets (static indexing), kt+=2 unroll
    short8 a0[7], b0[4], a1[7], b1[4];
    LOADSET(a0, b0, 0)
    for (int kt = 0; kt < NKT; kt += 2) {
        LOADSET(a1, b1, kt + 1)
        MFMASET(a0, b0)
        if (kt + 2 < NKT) LOADSET(a0, b0, kt + 2)
        MFMASET(a1, b1)
    }

    // ---- in-register top-3 over this wave's 112 rows, per owned column ----
    float T0[4], T1[4], T2[4];
#pragma unroll
    for (int j = 0; j < 4; ++j) { T0[j] = -1e30f; T1[j] = -1e30f; T2[j] = -1e30f; }
#pragma unroll
    for (int r = 0; r < 7; ++r)
#pragma unroll
        for (int j = 0; j < 4; ++j)
#pragma unroll
            for (int g = 0; g < 4; ++g) {
                int row = r * 64 + w * 16 + quad * 4 + g;   // C layout: row=quad*4+reg
                float v = (row < HW) ? acc[r][j][g] : -1e30f;
                ins3(T0[j], T1[j], T2[j], v);
            }

    // quad-butterfly merge (rows spread over lane bits 4,5)
#pragma unroll
    for (int j = 0; j < 4; ++j) {
#pragma unroll
        for (int d = 16; d <= 32; d <<= 1) {
            float o0 = __shfl_xor(T0[j], d, 64);
            float o1 = __shfl_xor(T1[j], d, 64);
            float o2 = __shfl_xor(T2[j], d, 64);
            ins3(T0[j], T1[j], T2[j], o0);
            ins3(T0[j], T1[j], T2[j], o1);
            ins3(T0[j], T1[j], T2[j], o2);
        }
    }

    // cross-wave merge via LDS
    if (quad == 0) {
#pragma unroll
        for (int j = 0; j < 4; ++j) {
            mrg[w][j * 16 + c16][0] = T0[j];
            mrg[w][j * 16 + c16][1] = T1[j];
            mrg[w][j * 16 + c16][2] = T2[j];
        }
    }
    __syncthreads();
    if (tid < 64) {
        int col = tid;
        float t0 = mrg[0][col][0], t1 = mrg[0][col][1], t2 = mrg[0][col][2];
#pragma unroll
        for (int ww = 1; ww < 4; ++ww) {
            ins3(t0, t1, t2, mrg[ww][col][0]);
            ins3(t0, t1, t2, mrg[ww][col][1]);
            ins3(t0, t1, t2, mrg[ww][col][2]);
        }
        float s = (mt * 64 + col < HW) ? (t0 + t1 + t2) : 0.f;
#pragma unroll
        for (int d = 32; d >= 1; d >>= 1) s += __shfl_xor(s, d, 64);
        if (tid == 0) atomicAdd(&out[b * N_CLS + n], s);
    }
}

extern "C" void kernel_launch(void* const* d_in, const int* in_sizes, int n_in,
                              void* d_out, int out_size, void* d_ws, size_t ws_size,
                              hipStream_t stream) {
    const float* q = (const float*)d_in[0];
    const float* S = (const float*)d_in[1];
    float* out = (float*)d_out;

    char* ws = (char*)d_ws;
    size_t off = 0;
    __hip_bfloat16* qn2 = (__hip_bfloat16*)(ws + off);
    off += (size_t)B_IMGS * NRB * NKT * CHUNK * 2;  off = (off + 255) & ~(size_t)255;
    __hip_bfloat16* sn2 = (__hip_bfloat16*)(ws + off);

    // 2 dispatches total: fused prep (also zeroes out) -> gemm
    prep_kernel<<<dim3(80 * 7), dim3(256), 0, stream>>>(q, S, qn2, sn2, out);
    // 8 XCD groups x 350 slots (35 blocks/image); b>=75 slots exit immediately
    gemm_top3_kernel<<<dim3(8 * 350), dim3(256), 0, stream>>>(qn2, sn2, out);
}